// Round 3
// baseline (341.226 us; speedup 1.0000x reference)
//
#include <hip/hip_runtime.h>
#include <float.h>

#define BB 256
#define DD 256
#define KK 1024
#define EE 16
#define DECAY 0.999f
#define GAIN  0.001f
#define EPS   1e-6f

// output offsets in floats (tuple order: cw_embed, one_hot, new_codebook, new_ema)
#define OH_OFF   ((size_t)BB * DD * EE)                    // 1048576
#define CB_OFF   (OH_OFF + (size_t)BB * DD * KK)           // 68157440
#define EMA_OFF  (CB_OFF + (size_t)DD * KK * EE)           // 72351744

typedef float f32x4 __attribute__((ext_vector_type(4)));

__device__ __forceinline__ float dot16(const float4& a0, const float4& a1,
                                       const float4& a2, const float4& a3,
                                       const float4& b0, const float4& b1,
                                       const float4& b2, const float4& b3) {
  float s = a0.x * b0.x;
  s = fmaf(a0.y, b0.y, s); s = fmaf(a0.z, b0.z, s); s = fmaf(a0.w, b0.w, s);
  s = fmaf(a1.x, b1.x, s); s = fmaf(a1.y, b1.y, s); s = fmaf(a1.z, b1.z, s); s = fmaf(a1.w, b1.w, s);
  s = fmaf(a2.x, b2.x, s); s = fmaf(a2.y, b2.y, s); s = fmaf(a2.z, b2.z, s); s = fmaf(a2.w, b2.w, s);
  s = fmaf(a3.x, b3.x, s); s = fmaf(a3.y, b3.y, s); s = fmaf(a3.z, b3.z, s); s = fmaf(a3.w, b3.w, s);
  return s;
}

// monotonic ordered-uint of an f32; key = ord<<32 | k. atomicMin -> smallest
// dist, lowest k on exact ties (identical to strict-< ascending-k scan).
__device__ __forceinline__ unsigned long long packkey(float dist, int k) {
  unsigned u = __float_as_uint(dist);
  unsigned m = ((int)u < 0) ? 0xFFFFFFFFu : 0x80000000u;
  return ((unsigned long long)(u ^ m) << 32) | (unsigned long long)(unsigned)k;
}

__device__ __forceinline__ void ntst4(float4* p, float4 v) {
  f32x4 t = { v.x, v.y, v.z, v.w };
  __builtin_nontemporal_store(t, (f32x4*)p);
}

// ---------------- Kernel 1: per-d argmin + cw_embed/new_codebook/new_ema ----
// One block per d, 1024 threads = 16 waves, each wave scans 64 k's.
// NO one_hot traffic here (moved to kernel 2 for linear streaming); instead
// the argmin index for (b, d) is stashed as an int at the start of one_hot
// row b (one_hot[b][0][d]), which kernel 2 reads and then overwrites.
__global__ __launch_bounds__(1024) void vqvae_main(
    const float* __restrict__ cw_q,      // (B, D*E)
    const float* __restrict__ codebook,  // (D, K, E)
    const float* __restrict__ ema,       // (D, K)
    float* __restrict__ out)
{
  __shared__ float4 cb4s[KK * EE / 4];            // 64 KB codebook row d
  __shared__ float4 upd4s[KK * EE / 4];           // 64 KB update accumulator
  __shared__ float  c2s[KK];                      // 4 KB |c|^2
  __shared__ float  esh[KK];                      // 4 KB old ema (prefetched)
  __shared__ float  cnts[KK];                     // 4 KB
  __shared__ unsigned long long amin[BB];         // 2 KB packed argmin
  __shared__ int    ish[BB];                      // 1 KB

  const int t = threadIdx.x;
  const int d = blockIdx.x;
  const int w = t >> 6;
  const int l = t & 63;
  const float4 z4 = make_float4(0.f, 0.f, 0.f, 0.f);

  // ---- P0: init LDS, prefetch ema, stage codebook, load x fragments ----
  cnts[t] = 0.f;
  if (t < BB) amin[t] = ~0ULL;
  esh[t] = ema[(size_t)d * KK + t];
  #pragma unroll
  for (int i = 0; i < 4; ++i) upd4s[i * 1024 + t] = z4;

  const float4* src4 = (const float4*)codebook + (size_t)d * (KK * EE / 4);
  #pragma unroll
  for (int i = 0; i < 4; ++i) {
    int i4 = i * 1024 + t;
    float4 v = src4[i4];
    cb4s[i4] = v;
    float sq = v.x * v.x;
    sq = fmaf(v.y, v.y, sq);
    sq = fmaf(v.z, v.z, sq);
    sq = fmaf(v.w, v.w, sq);
    sq += __shfl_xor(sq, 1);
    sq += __shfl_xor(sq, 2);
    if ((t & 3) == 0) c2s[i4 >> 2] = sq;
  }

  float4 xv[4][4];
  float  x2[4];
  #pragma unroll
  for (int j = 0; j < 4; ++j) {
    const int b = l + 64 * j;
    const float4* xr = (const float4*)cw_q + (size_t)b * (DD * EE / 4) + d * 4;
    xv[j][0] = xr[0]; xv[j][1] = xr[1]; xv[j][2] = xr[2]; xv[j][3] = xr[3];
  }
  #pragma unroll
  for (int j = 0; j < 4; ++j)
    x2[j] = dot16(xv[j][0], xv[j][1], xv[j][2], xv[j][3],
                  xv[j][0], xv[j][1], xv[j][2], xv[j][3]);

  __syncthreads();

  // ---- P1: scan — wave w covers k in [64w, 64w+64), pure LDS+VALU ----
  float best[4] = {FLT_MAX, FLT_MAX, FLT_MAX, FLT_MAX};
  int   bi[4]   = {0, 0, 0, 0};
  const int kbase = w << 6;

  #pragma unroll 2
  for (int s = 0; s < 64; ++s) {
    const int k = kbase + s;
    const float4* p = cb4s + (k << 2);     // wave-uniform -> LDS broadcast
    float4 c0 = p[0], c1 = p[1], c2v = p[2], c3 = p[3];
    const float c2k = c2s[k];
    #pragma unroll
    for (int j = 0; j < 4; ++j) {
      float dj = dot16(c0, c1, c2v, c3, xv[j][0], xv[j][1], xv[j][2], xv[j][3]);
      float dist = fmaf(-2.f, dj, x2[j] + c2k);
      if (dist < best[j]) { best[j] = dist; bi[j] = k; }   // strict <: lowest k wins
    }
  }
  #pragma unroll
  for (int j = 0; j < 4; ++j)
    atomicMin(&amin[l + 64 * j], packkey(best[j], bi[j]));

  __syncthreads();

  // ---- P2: epilogue per b + prefetch scatter operands ----
  const int e = t & 15;
  const int g = t >> 4;                    // 64 groups handle 4 b's each
  float xpre[4];
  #pragma unroll
  for (int i = 0; i < 4; ++i)
    xpre[i] = cw_q[(size_t)(g * 4 + i) * (DD * EE) + (size_t)d * EE + e];

  if (t < BB) {
    const int b = t;
    unsigned long long key = amin[b];
    const int bidx = (int)(unsigned)(key & 0xFFFFFFFFull);

    float4* ce = (float4*)out + (size_t)b * (DD * EE / 4) + d * 4;
    const float4* cwp = cb4s + (bidx << 2);
    ntst4(&ce[0], cwp[0]); ntst4(&ce[1], cwp[1]);
    ntst4(&ce[2], cwp[2]); ntst4(&ce[3], cwp[3]);

    // stash idx for kernel 2 at one_hot[b][0][d] (normal store: keep L2-hot)
    ((int*)(out + OH_OFF))[(size_t)b * (DD * KK) + d] = bidx;

    ish[b] = bidx;
    atomicAdd(&cnts[bidx], 1.0f);
  }
  __syncthreads();

  // ---- P3+P4 merged: update scatter (e-split banks) + new_ema ----
  {
    float* upd = (float*)upd4s;
    #pragma unroll
    for (int i = 0; i < 4; ++i) {
      int k = ish[g * 4 + i];
      atomicAdd(&upd[k * EE + e], xpre[i]);
    }
    float* oe = out + EMA_OFF + (size_t)d * KK;
    __builtin_nontemporal_store(DECAY * esh[t] + GAIN * cnts[t], &oe[t]);
  }
  __syncthreads();

  // ---- P5: new_codebook ----
  {
    float4* ocb = (float4*)(out + CB_OFF) + (size_t)d * (KK * EE / 4);
    #pragma unroll
    for (int i = 0; i < 4; ++i) {
      int i4 = i * 1024 + t;
      int k  = i4 >> 2;
      float4 c = cb4s[i4];
      float4 u = upd4s[i4];
      float inv = GAIN / (esh[k] + EPS);
      float4 r;
      r.x = DECAY * c.x + u.x * inv;
      r.y = DECAY * c.y + u.y * inv;
      r.z = DECAY * c.z + u.z * inv;
      r.w = DECAY * c.w + u.w * inv;
      ntst4(&ocb[i4], r);
    }
  }
}

// ---------------- Kernel 2: one_hot linear stream ---------------------------
// One block per b. Stage the 256 stashed idx ints to LDS, then stream the
// contiguous 1 MB row (65536 float4, fully coalesced, NT) with the 1.0s
// fused into the sweep. Same linear pattern the 6.3 TB/s fill uses.
__global__ __launch_bounds__(1024) void vqvae_onehot(float* __restrict__ out)
{
  __shared__ int ksh[DD];
  const int b = blockIdx.x;
  const int t = threadIdx.x;
  float* row = out + OH_OFF + (size_t)b * (DD * KK);

  if (t < DD) ksh[t] = ((const int*)row)[t];
  __syncthreads();   // drains the stash loads before we overwrite the region

  float4* row4 = (float4*)row;
  const int rel = (t & 255) << 2;   // element base within this thread's d-chunk
  const int tq  = t >> 8;           // which of the 4 d's per i this thread hits

  #pragma unroll 4
  for (int i = 0; i < 64; ++i) {
    const int hot = ksh[i * 4 + tq];          // wave-uniform -> LDS broadcast
    float4 v;
    v.x = (rel     == hot) ? 1.0f : 0.0f;
    v.y = (rel + 1 == hot) ? 1.0f : 0.0f;
    v.z = (rel + 2 == hot) ? 1.0f : 0.0f;
    v.w = (rel + 3 == hot) ? 1.0f : 0.0f;
    ntst4(&row4[i * 1024 + t], v);            // f = i*1024+t: coalesced, linear
  }
}

extern "C" void kernel_launch(void* const* d_in, const int* in_sizes, int n_in,
                              void* d_out, int out_size, void* d_ws, size_t ws_size,
                              hipStream_t stream) {
  const float* cw_q     = (const float*)d_in[0];
  const float* codebook = (const float*)d_in[1];
  const float* ema      = (const float*)d_in[2];
  float* out = (float*)d_out;
  (void)in_sizes; (void)n_in; (void)out_size; (void)d_ws; (void)ws_size;

  vqvae_main<<<dim3(DD), dim3(1024), 0, stream>>>(cw_q, codebook, ema, out);
  vqvae_onehot<<<dim3(BB), dim3(1024), 0, stream>>>(out);
}

// Round 4
// 336.726 us; speedup vs baseline: 1.0134x; 1.0134x over previous
//
#include <hip/hip_runtime.h>
#include <float.h>

#define BB 256
#define DD 256
#define KK 1024
#define EE 16
#define DECAY 0.999f
#define GAIN  0.001f
#define EPS   1e-6f

// output offsets in floats (tuple order: cw_embed, one_hot, new_codebook, new_ema)
#define OH_OFF   ((size_t)BB * DD * EE)                    // 1048576
#define CB_OFF   (OH_OFF + (size_t)BB * DD * KK)           // 68157440
#define EMA_OFF  (CB_OFF + (size_t)DD * KK * EE)           // 72351744

#define ROW      (DD * KK)                                 // 262144 floats / one_hot row
#define TAILF    (ROW - 256)                               // 261888: last 256 floats = stash
#define TAIL4    (ROW / 4 - 64)                            // 65472: first excluded float4

typedef float f32x4 __attribute__((ext_vector_type(4)));

__device__ __forceinline__ float dot16(const float4& a0, const float4& a1,
                                       const float4& a2, const float4& a3,
                                       const float4& b0, const float4& b1,
                                       const float4& b2, const float4& b3) {
  float s = a0.x * b0.x;
  s = fmaf(a0.y, b0.y, s); s = fmaf(a0.z, b0.z, s); s = fmaf(a0.w, b0.w, s);
  s = fmaf(a1.x, b1.x, s); s = fmaf(a1.y, b1.y, s); s = fmaf(a1.z, b1.z, s); s = fmaf(a1.w, b1.w, s);
  s = fmaf(a2.x, b2.x, s); s = fmaf(a2.y, b2.y, s); s = fmaf(a2.z, b2.z, s); s = fmaf(a2.w, b2.w, s);
  s = fmaf(a3.x, b3.x, s); s = fmaf(a3.y, b3.y, s); s = fmaf(a3.z, b3.z, s); s = fmaf(a3.w, b3.w, s);
  return s;
}

// monotonic ordered-uint of an f32; key = ord<<32 | k. atomicMin -> smallest
// dist, lowest k on exact ties (identical to strict-< ascending-k scan).
__device__ __forceinline__ unsigned long long packkey(float dist, int k) {
  unsigned u = __float_as_uint(dist);
  unsigned m = ((int)u < 0) ? 0xFFFFFFFFu : 0x80000000u;
  return ((unsigned long long)(u ^ m) << 32) | (unsigned long long)(unsigned)k;
}

__device__ __forceinline__ void ntst4(float4* p, float4 v) {
  f32x4 t = { v.x, v.y, v.z, v.w };
  __builtin_nontemporal_store(t, (f32x4*)p);
}

// ---------------- Kernel 1: per-d block --------------------------------------
// Identical schedule to the 318us R1 kernel (16 waves, interleaved store
// stream + scan), EXCEPT the one_hot zero stream now targets the block's OWN
// linear 1 MB row (b = d) instead of 256 scattered 4KB chunks — controlled
// test of the store-address-pattern theory. The last 1 KB of each row is NOT
// zeroed here; instead every block d stashes idx[b][d] (int) into row b's
// tail, which kernel 2 reads (coalesced) and overwrites with correct values.
__global__ __launch_bounds__(1024) void vqvae_main(
    const float* __restrict__ cw_q,      // (B, D*E)
    const float* __restrict__ codebook,  // (D, K, E)
    const float* __restrict__ ema,       // (D, K)
    float* __restrict__ out)
{
  __shared__ float4 cb4s[KK * EE / 4];            // 64 KB codebook row d
  __shared__ float4 upd4s[KK * EE / 4];           // 64 KB update accumulator
  __shared__ float  c2s[KK];                      // 4 KB |c|^2
  __shared__ float  esh[KK];                      // 4 KB old ema (prefetched)
  __shared__ float  cnts[KK];                     // 4 KB
  __shared__ unsigned long long amin[BB];         // 2 KB packed argmin
  __shared__ int    ish[BB];                      // 1 KB

  const int t = threadIdx.x;
  const int d = blockIdx.x;
  const int w = t >> 6;
  const int l = t & 63;
  const float4 z4 = make_float4(0.f, 0.f, 0.f, 0.f);

  float4* zb4 = (float4*)(out + OH_OFF + (size_t)d * ROW);   // own linear row

  // ---- P0: init LDS, prefetch ema, stage codebook, load x fragments ----
  cnts[t] = 0.f;
  if (t < BB) amin[t] = ~0ULL;
  esh[t] = ema[(size_t)d * KK + t];
  #pragma unroll
  for (int i = 0; i < 4; ++i) upd4s[i * 1024 + t] = z4;

  // prologue zero stream: first 8/64 slices overlap the staging loads
  #pragma unroll
  for (int j = 0; j < 8; ++j) ntst4(&zb4[j * 1024 + t], z4);

  const float4* src4 = (const float4*)codebook + (size_t)d * (KK * EE / 4);
  #pragma unroll
  for (int i = 0; i < 4; ++i) {
    int i4 = i * 1024 + t;
    float4 v = src4[i4];
    cb4s[i4] = v;
    float sq = v.x * v.x;
    sq = fmaf(v.y, v.y, sq);
    sq = fmaf(v.z, v.z, sq);
    sq = fmaf(v.w, v.w, sq);
    sq += __shfl_xor(sq, 1);
    sq += __shfl_xor(sq, 2);
    if ((t & 3) == 0) c2s[i4 >> 2] = sq;
  }

  float4 xv[4][4];
  float  x2[4];
  #pragma unroll
  for (int j = 0; j < 4; ++j) {
    const int b = l + 64 * j;
    const float4* xr = (const float4*)cw_q + (size_t)b * (DD * EE / 4) + d * 4;
    xv[j][0] = xr[0]; xv[j][1] = xr[1]; xv[j][2] = xr[2]; xv[j][3] = xr[3];
  }
  #pragma unroll
  for (int j = 0; j < 4; ++j)
    x2[j] = dot16(xv[j][0], xv[j][1], xv[j][2], xv[j][3],
                  xv[j][0], xv[j][1], xv[j][2], xv[j][3]);

  __syncthreads();

  // ---- P1: scan (wave w covers k in [64w, 64w+64)) + linear zero stream ----
  float best[4] = {FLT_MAX, FLT_MAX, FLT_MAX, FLT_MAX};
  int   bi[4]   = {0, 0, 0, 0};
  const int kbase = w << 6;

  #pragma unroll 1
  for (int s = 0; s < 56; ++s) {
    const int k = kbase + s;
    const float4* p = cb4s + (k << 2);     // wave-uniform -> LDS broadcast
    float4 c0 = p[0], c1 = p[1], c2v = p[2], c3 = p[3];
    const float c2k = c2s[k];
    #pragma unroll
    for (int j = 0; j < 4; ++j) {
      float dj = dot16(c0, c1, c2v, c3, xv[j][0], xv[j][1], xv[j][2], xv[j][3]);
      float dist = fmaf(-2.f, dj, x2[j] + c2k);
      if (dist < best[j]) { best[j] = dist; bi[j] = k; }   // strict <: lowest k wins
    }
    // remaining 56/64 slices of the linear row (slice 8+s), tail excluded
    const int f = (8 + s) * 1024 + t;
    if (f < TAIL4) ntst4(&zb4[f], z4);
  }
  #pragma unroll 1
  for (int s = 56; s < 64; ++s) {
    const int k = kbase + s;
    const float4* p = cb4s + (k << 2);
    float4 c0 = p[0], c1 = p[1], c2v = p[2], c3 = p[3];
    const float c2k = c2s[k];
    #pragma unroll
    for (int j = 0; j < 4; ++j) {
      float dj = dot16(c0, c1, c2v, c3, xv[j][0], xv[j][1], xv[j][2], xv[j][3]);
      float dist = fmaf(-2.f, dj, x2[j] + c2k);
      if (dist < best[j]) { best[j] = dist; bi[j] = k; }
    }
  }

  #pragma unroll
  for (int j = 0; j < 4; ++j)
    atomicMin(&amin[l + 64 * j], packkey(best[j], bi[j]));

  __syncthreads();   // drains zero-stream vmcnt + amin atomics

  // ---- P2: epilogue per b + prefetch scatter operands ----
  const int e = t & 15;
  const int g = t >> 4;                    // 64 groups handle 4 b's each
  float xpre[4];
  #pragma unroll
  for (int i = 0; i < 4; ++i)
    xpre[i] = cw_q[(size_t)(g * 4 + i) * (DD * EE) + (size_t)d * EE + e];

  if (t < BB) {
    const int b = t;
    unsigned long long key = amin[b];
    const int bidx = (int)(unsigned)(key & 0xFFFFFFFFull);

    float4* ce = (float4*)out + (size_t)b * (DD * EE / 4) + d * 4;
    const float4* cwp = cb4s + (bidx << 2);
    ntst4(&ce[0], cwp[0]); ntst4(&ce[1], cwp[1]);
    ntst4(&ce[2], cwp[2]); ntst4(&ce[3], cwp[3]);

    // stash idx[b][d] into row b's tail (region excluded from zero-fill; no race)
    ((int*)(out + OH_OFF))[(size_t)b * ROW + TAILF + d] = bidx;

    ish[b] = bidx;
    atomicAdd(&cnts[bidx], 1.0f);
  }
  __syncthreads();

  // ---- P3+P4 merged: update scatter (e-split banks) + new_ema ----
  {
    float* upd = (float*)upd4s;
    #pragma unroll
    for (int i = 0; i < 4; ++i) {
      int k = ish[g * 4 + i];
      atomicAdd(&upd[k * EE + e], xpre[i]);
    }
    float* oe = out + EMA_OFF + (size_t)d * KK;
    __builtin_nontemporal_store(DECAY * esh[t] + GAIN * cnts[t], &oe[t]);
  }
  __syncthreads();

  // ---- P5: new_codebook ----
  {
    float4* ocb = (float4*)(out + CB_OFF) + (size_t)d * (KK * EE / 4);
    #pragma unroll
    for (int i = 0; i < 4; ++i) {
      int i4 = i * 1024 + t;
      int k  = i4 >> 2;
      float4 c = cb4s[i4];
      float4 u = upd4s[i4];
      float inv = GAIN / (esh[k] + EPS);
      float4 r;
      r.x = DECAY * c.x + u.x * inv;
      r.y = DECAY * c.y + u.y * inv;
      r.z = DECAY * c.z + u.z * inv;
      r.w = DECAY * c.w + u.w * inv;
      ntst4(&ocb[i4], r);
    }
  }
}

// ---------------- Kernel 2: ones + tail fix-up (tiny, ~10 us) ---------------
// Block b: read row b's 256-int stash (coalesced, L2-hot), rewrite the 1 KB
// tail with correct zeros/ones, scatter the 256 ones within its own 1 MB row.
__global__ __launch_bounds__(256) void vqvae_ones(float* __restrict__ out)
{
  __shared__ int ksh[DD];
  const int b = blockIdx.x;
  const int t = threadIdx.x;
  float* row = out + OH_OFF + (size_t)b * ROW;

  ksh[t] = ((const int*)row)[TAILF + t];
  __syncthreads();

  const int k255 = ksh[255];
  // tail: elements (d=255, k=768+t) — includes d=255's one if k255 >= 768
  row[TAILF + t] = (768 + t == k255) ? 1.0f : 0.0f;
  // main ones: (d=t, k=ksh[t]); d=255 handled above when its one lies in tail
  if (t < 255 || k255 < 768)
    row[(size_t)t * KK + ksh[t]] = 1.0f;
}

extern "C" void kernel_launch(void* const* d_in, const int* in_sizes, int n_in,
                              void* d_out, int out_size, void* d_ws, size_t ws_size,
                              hipStream_t stream) {
  const float* cw_q     = (const float*)d_in[0];
  const float* codebook = (const float*)d_in[1];
  const float* ema      = (const float*)d_in[2];
  float* out = (float*)d_out;
  (void)in_sizes; (void)n_in; (void)out_size; (void)d_ws; (void)ws_size;

  vqvae_main<<<dim3(DD), dim3(1024), 0, stream>>>(cw_q, codebook, ema, out);
  vqvae_ones<<<dim3(BB), dim3(256), 0, stream>>>(out);
}